// Round 7
// baseline (83.319 us; speedup 1.0000x reference)
//
#include <hip/hip_runtime.h>

#define NB 4
#define NE 16
#define NHW (512*512)
#define NINST 32
#define DELTA_VAR 0.5f
#define DELTA_DIST 1.5f
#define ALPHA 1.0f
#define BETA 1.0f
#define GAMMA 0.001f

typedef __attribute__((ext_vector_type(8))) short short8;
typedef __attribute__((ext_vector_type(4))) float f32x4;

// ---- k_hist geometry (round-4 best): 512 blocks x 256 thr (4 waves) ----
#define GRID_H 512
#define BLK_H 256
#define BPB_H (GRID_H/NB)            // 128 blocks per batch
#define PXB_H (NHW/BPB_H)            // 2048 px per block
#define CHUNKS_H 16                  // 4 waves * 16 chunks * 32 px = 2048
#define PH_STRIDE 544                // [32][16] sums + [32] counts

// ---- k_var geometry: 1024 blocks x 256 thr, 4 px/thread, one-shot ----
#define GRID_V 1024
#define BLK_V 256

// ---- ws layout (floats); every slot written before read each call ----
#define P_HIST 0                             // [NB][PH_STRIDE][BPB_H] transposed partials
#define T_MEAN (GRID_H*PH_STRIDE)            // [NB][33*16], label 0 = zeros
#define T_MEAN_SZ (33*NE)
#define T_DIST (T_MEAN + NB*T_MEAN_SZ)
#define T_REG  (T_DIST + NB)
#define T_NS   (T_REG + NB)
#define VACC   (T_NS + NB)                   // [NB] var accumulators (atomic)
#define VCNT   (VACC + NB)                   // 1 x u32 completion counter

#define MTSTR 34                             // transposed mean row stride

__device__ __forceinline__ unsigned f2bf(float x) {
    unsigned u = __builtin_bit_cast(unsigned, x);
    return (u + 0x7FFFu + ((u >> 16) & 1u)) >> 16;   // RNE bf16
}

__device__ __forceinline__ float wave_sum(float v) {
    #pragma unroll
    for (int o = 32; o > 0; o >>= 1) v += __shfl_down(v, o, 64);
    return v;
}

union PK { unsigned u[4]; short8 s; };

__global__ __launch_bounds__(BLK_H) void k_hist(const float* __restrict__ emb,
        const int* __restrict__ lab, float* __restrict__ ws) {
    __shared__ float red[4][2*NE][17];
    __shared__ float redc[4][2*NE];
    const int t = threadIdx.x;
    const int lane = t & 63;
    const int wv = t >> 6;
    const int colg = lane >> 4;
    const int cm = lane & 15;
    const int b = blockIdx.x / BPB_H;
    const int blk = blockIdx.x % BPB_H;

    const float* ebase = emb + (size_t)b*(NE*NHW) + (size_t)cm*NHW;
    const int* lbase = lab + (size_t)b*NHW;

    f32x4 acc_s0 = {0.f,0.f,0.f,0.f}, acc_s1 = {0.f,0.f,0.f,0.f};
    f32x4 acc_c0 = {0.f,0.f,0.f,0.f}, acc_c1 = {0.f,0.f,0.f,0.f};
    PK ones; ones.u[0]=ones.u[1]=ones.u[2]=ones.u[3]=0x3F803F80u;

    const int base = blk*PXB_H + wv*(PXB_H/4);
    #pragma unroll 4
    for (int it = 0; it < CHUNKS_H; ++it) {
        const int ko = base + it*32 + colg*8;
        const float4 v0 = *(const float4*)(ebase + ko);
        const float4 v1 = *(const float4*)(ebase + ko + 4);
        const int4 L0 = *(const int4*)(lbase + ko);
        const int4 L1 = *(const int4*)(lbase + ko + 4);
        PK bf;
        bf.u[0] = f2bf(v0.x) | (f2bf(v0.y) << 16);
        bf.u[1] = f2bf(v0.z) | (f2bf(v0.w) << 16);
        bf.u[2] = f2bf(v1.x) | (f2bf(v1.y) << 16);
        bf.u[3] = f2bf(v1.z) | (f2bf(v1.w) << 16);
        const int la[8] = {L0.x,L0.y,L0.z,L0.w,L1.x,L1.y,L1.z,L1.w};
        PK a0, a1;
        #pragma unroll
        for (int p = 0; p < 4; ++p) {
            const unsigned lo0 = (la[2*p]   == cm+1 ) ? 0x3F80u : 0u;
            const unsigned hi0 = (la[2*p+1] == cm+1 ) ? 0x3F80u : 0u;
            const unsigned lo1 = (la[2*p]   == cm+17) ? 0x3F80u : 0u;
            const unsigned hi1 = (la[2*p+1] == cm+17) ? 0x3F80u : 0u;
            a0.u[p] = lo0 | (hi0 << 16);
            a1.u[p] = lo1 | (hi1 << 16);
        }
        acc_s0 = __builtin_amdgcn_mfma_f32_16x16x32_bf16(a0.s, bf.s,   acc_s0, 0,0,0);
        acc_s1 = __builtin_amdgcn_mfma_f32_16x16x32_bf16(a1.s, bf.s,   acc_s1, 0,0,0);
        acc_c0 = __builtin_amdgcn_mfma_f32_16x16x32_bf16(a0.s, ones.s, acc_c0, 0,0,0);
        acc_c1 = __builtin_amdgcn_mfma_f32_16x16x32_bf16(a1.s, ones.s, acc_c1, 0,0,0);
    }
    // D layout: col = lane&15 (channel), row = colg*4 + r (seg within half)
    #pragma unroll
    for (int r = 0; r < 4; ++r) {
        red[wv][colg*4 + r][cm]      = acc_s0[r];
        red[wv][16 + colg*4 + r][cm] = acc_s1[r];
    }
    if (cm == 0) {
        #pragma unroll
        for (int r = 0; r < 4; ++r) {
            redc[wv][colg*4 + r]      = acc_c0[r];
            redc[wv][16 + colg*4 + r] = acc_c1[r];
        }
    }
    __syncthreads();
    // transposed partial store: [b][item][blk]
    float* dst = ws + P_HIST + (size_t)b*PH_STRIDE*BPB_H + blk;
    for (int i = t; i < PH_STRIDE; i += BLK_H) {
        float v;
        if (i < 512) {
            const int s = i >> 4, e = i & 15;
            v = red[0][s][e] + red[1][s][e] + red[2][s][e] + red[3][s][e];
        } else {
            const int s = i - 512;
            v = redc[0][s] + redc[1][s] + redc[2][s] + redc[3][s];
        }
        dst[(size_t)i*BPB_H] = v;
    }
}

__global__ void k_stats(float* __restrict__ ws) {
    const int b = blockIdx.x;
    const int t = threadIdx.x;
    __shared__ float lred[PH_STRIDE];
    __shared__ float lmean[NINST*17];
    __shared__ float lcnt[NINST];
    __shared__ int lpres[NINST];
    const float* ph = ws + P_HIST + (size_t)b*PH_STRIDE*BPB_H;
    for (int i = t; i < PH_STRIDE; i += 256) {
        const float4* r4 = (const float4*)(ph + (size_t)i*BPB_H);
        float4 s4 = {0.f,0.f,0.f,0.f};
        #pragma unroll 8
        for (int k = 0; k < BPB_H/4; k++) {
            const float4 v = r4[k];
            s4.x += v.x; s4.y += v.y; s4.z += v.z; s4.w += v.w;
        }
        lred[i] = s4.x + s4.y + s4.z + s4.w;
    }
    __syncthreads();
    if (t < NINST) {
        const float c = lred[512 + t];
        lcnt[t] = c;
        lpres[t] = (c > 0.f) ? 1 : 0;
    }
    if (t == 0) {
        ws[VACC + b] = 0.f;
        if (b == 0) ((unsigned*)ws)[VCNT] = 0u;
    }
    __syncthreads();
    for (int i = t; i < 512; i += 256) {
        const int s = i >> 4, e = i & 15;
        lmean[s*17 + e] = lred[i] / fmaxf(lcnt[s], 1.f);
    }
    __syncthreads();
    for (int i = t; i < 33*NE; i += 256) {
        const int l = i >> 4, e = i & 15;
        ws[T_MEAN + b*T_MEAN_SZ + i] = (l == 0) ? 0.f : lmean[(l-1)*17 + e];
    }
    if (t < 64) {
        const int lane = t;
        const int n = __popcll(__ballot((lane < NINST) ? (lpres[lane] != 0) : false));
        float dsum = 0.f;
        for (int idx = lane; idx < NINST*NINST; idx += 64) {
            const int i = idx >> 5, j = idx & 31;
            if (i < j && lpres[i] && lpres[j]) {
                float d2 = 0.f;
                #pragma unroll
                for (int e = 0; e < NE; e++) {
                    const float df = lmean[i*17+e] - lmean[j*17+e];
                    d2 += df*df;
                }
                dsum += fmaxf(2.f*DELTA_DIST - sqrtf(d2), 0.f);
            }
        }
        dsum = wave_sum(dsum);
        float rsum = 0.f;
        if (lane < NINST && lpres[lane]) {
            float s2 = 0.f;
            #pragma unroll
            for (int e = 0; e < NE; e++) { const float m = lmean[lane*17+e]; s2 += m*m; }
            rsum = sqrtf(s2);
        }
        rsum = wave_sum(rsum);
        if (lane == 0) {
            const float nf = (float)n;
            const float nsafe = fmaxf(nf, 1.f);
            ws[T_DIST+b] = (n > 1) ? dsum / fmaxf(nf*(nf-1.f)*0.5f, 1.f) : 0.f;
            ws[T_REG+b] = rsum / nsafe;
            ws[T_NS+b] = nsafe;
        }
    }
}

__global__ __launch_bounds__(BLK_V, 4) void k_var(const float* __restrict__ emb,
        const int* __restrict__ lab, float* __restrict__ ws, float* __restrict__ out) {
    // transposed mean table: mt[e][lab], row stride 34 -> for uniform e, random
    // labels hit 33 consecutive banks (<=2-way aliasing = free per m136)
    __shared__ __align__(16) float mt[NE*MTSTR];
    __shared__ float wred[4];
    const int t = threadIdx.x;
    const int lane = t & 63;
    const int wv = t >> 6;
    const int b = blockIdx.x >> 8;
    const int blk = blockIdx.x & 255;

    const float* gmean = ws + T_MEAN + b*T_MEAN_SZ;
    for (int i = t; i < 33*NE; i += BLK_V) {
        const int l = i >> 4, e = i & 15;
        mt[e*MTSTR + l] = gmean[i];
    }
    __syncthreads();

    const float* ebase = emb + (size_t)b*(NE*NHW);
    const int* lbase = lab + (size_t)b*NHW;
    const int p = (blk*BLK_V + t)*4;
    const int4 l4 = *(const int4*)(lbase + p);
    float d0=0.f, d1=0.f, d2=0.f, d3=0.f;
    // channel-streaming: each v dies within its iteration -> low VGPR pressure,
    // 16 independent iterations pipeline many loads in flight
    #pragma unroll
    for (int e = 0; e < NE; e++) {
        const float4 v = *(const float4*)(ebase + (size_t)e*NHW + p);
        const float m0 = mt[e*MTSTR + l4.x];
        const float m1 = mt[e*MTSTR + l4.y];
        const float m2 = mt[e*MTSTR + l4.z];
        const float m3 = mt[e*MTSTR + l4.w];
        float df;
        df = v.x - m0; d0 += df*df;
        df = v.y - m1; d1 += df*df;
        df = v.z - m2; d2 += df*df;
        df = v.w - m3; d3 += df*df;
    }
    float acc = 0.f;
    if (l4.x > 0) acc += fmaxf(sqrtf(d0) - DELTA_VAR, 0.f);
    if (l4.y > 0) acc += fmaxf(sqrtf(d1) - DELTA_VAR, 0.f);
    if (l4.z > 0) acc += fmaxf(sqrtf(d2) - DELTA_VAR, 0.f);
    if (l4.w > 0) acc += fmaxf(sqrtf(d3) - DELTA_VAR, 0.f);

    const float wsum = wave_sum(acc);
    if (lane == 0) wred[wv] = wsum;
    __syncthreads();
    if (t == 0) {
        atomicAdd(&ws[VACC + b], wred[0]+wred[1]+wred[2]+wred[3]);
        __threadfence();
        const unsigned old = atomicAdd((unsigned*)&ws[VCNT], 1u);
        if (old == GRID_V - 1) {
            float tot = 0.f;
            #pragma unroll
            for (int bb = 0; bb < NB; bb++) {
                const float v = atomicAdd(&ws[VACC + bb], 0.f);   // coherent read
                tot += ALPHA * (v / ws[T_NS+bb])
                     + BETA * ws[T_DIST+bb]
                     + GAMMA * ws[T_REG+bb];
            }
            out[0] = tot * (1.f/NB);
        }
    }
}

extern "C" void kernel_launch(void* const* d_in, const int* in_sizes, int n_in,
                              void* d_out, int out_size, void* d_ws, size_t ws_size,
                              hipStream_t stream) {
    const float* emb = (const float*)d_in[0];
    const int* lab = (const int*)d_in[1];
    float* out = (float*)d_out;
    float* ws = (float*)d_ws;

    k_hist<<<GRID_H, BLK_H, 0, stream>>>(emb, lab, ws);
    k_stats<<<NB, 256, 0, stream>>>(ws);
    k_var<<<GRID_V, BLK_V, 0, stream>>>(emb, lab, ws, out);
}

// Round 8
// 74.058 us; speedup vs baseline: 1.1251x; 1.1251x over previous
//
#include <hip/hip_runtime.h>

#define NB 4
#define NE 16
#define NHW (512*512)
#define NINST 32
#define DELTA_VAR 0.5f
#define DELTA_DIST 1.5f
#define ALPHA 1.0f
#define BETA 1.0f
#define GAMMA 0.001f

typedef __attribute__((ext_vector_type(8))) short short8;
typedef __attribute__((ext_vector_type(4))) float f32x4;

// ---- k_hist geometry: 512 blocks x 256 thr (4 waves), 16 chunks/wave ----
#define GRID_H 512
#define BLK_H 256
#define BPB_H (GRID_H/NB)            // 128 blocks per batch
#define PXB_H (NHW/BPB_H)            // 2048 px per block
#define CHUNKS_H 16                  // 4 waves * 16 chunks * 32 px = 2048
#define PH_STRIDE 544                // [32][16] sums + [32] counts

// ---- k_var geometry: 1024 blocks x 256 thr, 4 px/thread, one-shot ----
#define GRID_V 1024
#define BLK_V 256

// ---- ws layout (floats); every slot written before read each call ----
#define P_HIST 0                             // [NB][PH_STRIDE][BPB_H] transposed partials
#define T_MEAN (GRID_H*PH_STRIDE)            // [NB][33*16], label 0 = zeros
#define T_MEAN_SZ (33*NE)
#define T_DIST (T_MEAN + NB*T_MEAN_SZ)
#define T_REG  (T_DIST + NB)
#define T_NS   (T_REG + NB)
#define VACC   (T_NS + NB)                   // [NB] var accumulators (atomic)
#define VCNT   (VACC + NB)                   // 1 x u32 completion counter

#define LMREP 4
#define LMSTR 660                            // 33*20 floats per replica (16B aligned)

__device__ __forceinline__ unsigned f2bf(float x) {
    unsigned u = __builtin_bit_cast(unsigned, x);
    return (u + 0x7FFFu + ((u >> 16) & 1u)) >> 16;   // RNE bf16
}

__device__ __forceinline__ float wave_sum(float v) {
    #pragma unroll
    for (int o = 32; o > 0; o >>= 1) v += __shfl_down(v, o, 64);
    return v;
}

union PK { unsigned u[4]; short8 s; };

__global__ __launch_bounds__(BLK_H) void k_hist(const float* __restrict__ emb,
        const int* __restrict__ lab, float* __restrict__ ws) {
    __shared__ float red[4][2*NE][17];
    __shared__ float redc[4][2*NE];
    const int t = threadIdx.x;
    const int lane = t & 63;
    const int wv = t >> 6;
    const int colg = lane >> 4;
    const int cm = lane & 15;
    const int b = blockIdx.x / BPB_H;
    const int blk = blockIdx.x % BPB_H;

    const float* ebase = emb + (size_t)b*(NE*NHW) + (size_t)cm*NHW;
    const int* lbase = lab + (size_t)b*NHW;

    f32x4 acc_s0 = {0.f,0.f,0.f,0.f}, acc_s1 = {0.f,0.f,0.f,0.f};
    f32x4 acc_c0 = {0.f,0.f,0.f,0.f}, acc_c1 = {0.f,0.f,0.f,0.f};
    PK ones; ones.u[0]=ones.u[1]=ones.u[2]=ones.u[3]=0x3F803F80u;

    const int base = blk*PXB_H + wv*(PXB_H/4);
    // software pipeline: issue chunk it+1's loads before consuming chunk it
    float4 cv0 = *(const float4*)(ebase + base + colg*8);
    float4 cv1 = *(const float4*)(ebase + base + colg*8 + 4);
    int4   cL0 = *(const int4*)(lbase + base + colg*8);
    int4   cL1 = *(const int4*)(lbase + base + colg*8 + 4);
    for (int it = 0; it < CHUNKS_H; ++it) {
        float4 nv0, nv1; int4 nL0, nL1;
        if (it + 1 < CHUNKS_H) {
            const int ko = base + (it+1)*32 + colg*8;
            nv0 = *(const float4*)(ebase + ko);
            nv1 = *(const float4*)(ebase + ko + 4);
            nL0 = *(const int4*)(lbase + ko);
            nL1 = *(const int4*)(lbase + ko + 4);
        }
        PK bf;
        bf.u[0] = f2bf(cv0.x) | (f2bf(cv0.y) << 16);
        bf.u[1] = f2bf(cv0.z) | (f2bf(cv0.w) << 16);
        bf.u[2] = f2bf(cv1.x) | (f2bf(cv1.y) << 16);
        bf.u[3] = f2bf(cv1.z) | (f2bf(cv1.w) << 16);
        const int la[8] = {cL0.x,cL0.y,cL0.z,cL0.w,cL1.x,cL1.y,cL1.z,cL1.w};
        PK a0, a1;
        #pragma unroll
        for (int p = 0; p < 4; ++p) {
            const unsigned lo0 = (la[2*p]   == cm+1 ) ? 0x3F80u : 0u;
            const unsigned hi0 = (la[2*p+1] == cm+1 ) ? 0x3F80u : 0u;
            const unsigned lo1 = (la[2*p]   == cm+17) ? 0x3F80u : 0u;
            const unsigned hi1 = (la[2*p+1] == cm+17) ? 0x3F80u : 0u;
            a0.u[p] = lo0 | (hi0 << 16);
            a1.u[p] = lo1 | (hi1 << 16);
        }
        acc_s0 = __builtin_amdgcn_mfma_f32_16x16x32_bf16(a0.s, bf.s,   acc_s0, 0,0,0);
        acc_s1 = __builtin_amdgcn_mfma_f32_16x16x32_bf16(a1.s, bf.s,   acc_s1, 0,0,0);
        acc_c0 = __builtin_amdgcn_mfma_f32_16x16x32_bf16(a0.s, ones.s, acc_c0, 0,0,0);
        acc_c1 = __builtin_amdgcn_mfma_f32_16x16x32_bf16(a1.s, ones.s, acc_c1, 0,0,0);
        cv0 = nv0; cv1 = nv1; cL0 = nL0; cL1 = nL1;
    }
    // D layout: col = lane&15 (channel), row = colg*4 + r (seg within half)
    #pragma unroll
    for (int r = 0; r < 4; ++r) {
        red[wv][colg*4 + r][cm]      = acc_s0[r];
        red[wv][16 + colg*4 + r][cm] = acc_s1[r];
    }
    if (cm == 0) {
        #pragma unroll
        for (int r = 0; r < 4; ++r) {
            redc[wv][colg*4 + r]      = acc_c0[r];
            redc[wv][16 + colg*4 + r] = acc_c1[r];
        }
    }
    __syncthreads();
    // transposed partial store: [b][item][blk]
    float* dst = ws + P_HIST + (size_t)b*PH_STRIDE*BPB_H + blk;
    for (int i = t; i < PH_STRIDE; i += BLK_H) {
        float v;
        if (i < 512) {
            const int s = i >> 4, e = i & 15;
            v = red[0][s][e] + red[1][s][e] + red[2][s][e] + red[3][s][e];
        } else {
            const int s = i - 512;
            v = redc[0][s] + redc[1][s] + redc[2][s] + redc[3][s];
        }
        dst[(size_t)i*BPB_H] = v;
    }
}

__global__ void k_stats(float* __restrict__ ws) {
    const int b = blockIdx.x;
    const int t = threadIdx.x;
    __shared__ float lred[PH_STRIDE];
    __shared__ float lmean[NINST*17];
    __shared__ float lcnt[NINST];
    __shared__ int lpres[NINST];
    const float* ph = ws + P_HIST + (size_t)b*PH_STRIDE*BPB_H;
    for (int i = t; i < PH_STRIDE; i += 256) {
        const float4* r4 = (const float4*)(ph + (size_t)i*BPB_H);
        float4 s4 = {0.f,0.f,0.f,0.f};
        #pragma unroll 8
        for (int k = 0; k < BPB_H/4; k++) {
            const float4 v = r4[k];
            s4.x += v.x; s4.y += v.y; s4.z += v.z; s4.w += v.w;
        }
        lred[i] = s4.x + s4.y + s4.z + s4.w;
    }
    __syncthreads();
    if (t < NINST) {
        const float c = lred[512 + t];
        lcnt[t] = c;
        lpres[t] = (c > 0.f) ? 1 : 0;
    }
    if (t == 0) {
        ws[VACC + b] = 0.f;
        if (b == 0) ((unsigned*)ws)[VCNT] = 0u;
    }
    __syncthreads();
    for (int i = t; i < 512; i += 256) {
        const int s = i >> 4, e = i & 15;
        lmean[s*17 + e] = lred[i] / fmaxf(lcnt[s], 1.f);
    }
    __syncthreads();
    for (int i = t; i < 33*NE; i += 256) {
        const int l = i >> 4, e = i & 15;
        ws[T_MEAN + b*T_MEAN_SZ + i] = (l == 0) ? 0.f : lmean[(l-1)*17 + e];
    }
    if (t < 64) {
        const int lane = t;
        const int n = __popcll(__ballot((lane < NINST) ? (lpres[lane] != 0) : false));
        float dsum = 0.f;
        for (int idx = lane; idx < NINST*NINST; idx += 64) {
            const int i = idx >> 5, j = idx & 31;
            if (i < j && lpres[i] && lpres[j]) {
                float d2 = 0.f;
                #pragma unroll
                for (int e = 0; e < NE; e++) {
                    const float df = lmean[i*17+e] - lmean[j*17+e];
                    d2 += df*df;
                }
                dsum += fmaxf(2.f*DELTA_DIST - sqrtf(d2), 0.f);
            }
        }
        dsum = wave_sum(dsum);
        float rsum = 0.f;
        if (lane < NINST && lpres[lane]) {
            float s2 = 0.f;
            #pragma unroll
            for (int e = 0; e < NE; e++) { const float m = lmean[lane*17+e]; s2 += m*m; }
            rsum = sqrtf(s2);
        }
        rsum = wave_sum(rsum);
        if (lane == 0) {
            const float nf = (float)n;
            const float nsafe = fmaxf(nf, 1.f);
            ws[T_DIST+b] = (n > 1) ? dsum / fmaxf(nf*(nf-1.f)*0.5f, 1.f) : 0.f;
            ws[T_REG+b] = rsum / nsafe;
            ws[T_NS+b] = nsafe;
        }
    }
}

// r4-measured-good k_var: prefetch ALL 17 loads, then __syncthreads (compiler
// emits s_waitcnt vmcnt(0) before s_barrier -> all loads in flight at once =
// max memory-level parallelism), then conflict-free LDS float4 gather.
__global__ __launch_bounds__(BLK_V) void k_var(const float* __restrict__ emb,
        const int* __restrict__ lab, float* __restrict__ ws, float* __restrict__ out) {
    __shared__ __align__(16) float lm[LMREP*LMSTR];
    __shared__ float wred[4];
    const int t = threadIdx.x;
    const int b = blockIdx.x >> 8;
    const int blk = blockIdx.x & 255;
    const float* ebase = emb + (size_t)b*(NE*NHW);
    const int* lbase = lab + (size_t)b*NHW;
    const int p = (blk*BLK_V + t)*4;

    // prefetch labels + all emb channels before the LDS fill + barrier
    const int4 l4 = *(const int4*)(lbase + p);
    float4 ev[NE];
    #pragma unroll
    for (int e = 0; e < NE; e++) ev[e] = *(const float4*)(ebase + (size_t)e*NHW + p);

    // 4 replicated mean tables, [33][20] each
    for (int i = t; i < 33*NE; i += BLK_V) {
        const int l = i >> 4, e = i & 15;
        const float v = ws[T_MEAN + b*T_MEAN_SZ + i];
        #pragma unroll
        for (int r = 0; r < LMREP; r++) lm[r*LMSTR + l*20 + e] = v;
    }
    __syncthreads();

    const float* lmc = lm + ((t >> 4) & (LMREP-1))*LMSTR;
    const float4* q0 = (const float4*)(lmc + l4.x*20);
    const float4* q1 = (const float4*)(lmc + l4.y*20);
    const float4* q2 = (const float4*)(lmc + l4.z*20);
    const float4* q3 = (const float4*)(lmc + l4.w*20);
    float d0=0.f, d1=0.f, d2=0.f, d3=0.f;
    #pragma unroll
    for (int c = 0; c < 4; c++) {
        const float4 ma = q0[c];
        const float4 mb = q1[c];
        const float4 mc_ = q2[c];
        const float4 md = q3[c];
        #pragma unroll
        for (int j = 0; j < 4; j++) {
            const float4 v = ev[4*c + j];
            float df;
            df = v.x - ((const float*)&ma)[j];  d0 += df*df;
            df = v.y - ((const float*)&mb)[j];  d1 += df*df;
            df = v.z - ((const float*)&mc_)[j]; d2 += df*df;
            df = v.w - ((const float*)&md)[j];  d3 += df*df;
        }
    }
    float acc = 0.f;
    if (l4.x > 0) acc += fmaxf(sqrtf(d0) - DELTA_VAR, 0.f);
    if (l4.y > 0) acc += fmaxf(sqrtf(d1) - DELTA_VAR, 0.f);
    if (l4.z > 0) acc += fmaxf(sqrtf(d2) - DELTA_VAR, 0.f);
    if (l4.w > 0) acc += fmaxf(sqrtf(d3) - DELTA_VAR, 0.f);

    const float wsum = wave_sum(acc);
    if ((t & 63) == 0) wred[t >> 6] = wsum;
    __syncthreads();
    if (t == 0) {
        atomicAdd(&ws[VACC + b], wred[0]+wred[1]+wred[2]+wred[3]);
        __threadfence();
        const unsigned old = atomicAdd((unsigned*)&ws[VCNT], 1u);
        if (old == GRID_V - 1) {
            float tot = 0.f;
            #pragma unroll
            for (int bb = 0; bb < NB; bb++) {
                const float v = atomicAdd(&ws[VACC + bb], 0.f);   // coherent read
                tot += ALPHA * (v / ws[T_NS+bb])
                     + BETA * ws[T_DIST+bb]
                     + GAMMA * ws[T_REG+bb];
            }
            out[0] = tot * (1.f/NB);
        }
    }
}

extern "C" void kernel_launch(void* const* d_in, const int* in_sizes, int n_in,
                              void* d_out, int out_size, void* d_ws, size_t ws_size,
                              hipStream_t stream) {
    const float* emb = (const float*)d_in[0];
    const int* lab = (const int*)d_in[1];
    float* out = (float*)d_out;
    float* ws = (float*)d_ws;

    k_hist<<<GRID_H, BLK_H, 0, stream>>>(emb, lab, ws);
    k_stats<<<NB, 256, 0, stream>>>(ws);
    k_var<<<GRID_V, BLK_V, 0, stream>>>(emb, lab, ws, out);
}